// Round 10
// baseline (126.192 us; speedup 1.0000x reference)
//
#include <hip/hip_runtime.h>
#include <math.h>

// Problem constants
#define BB 256
#define NE 400
#define NP (BB * NE)        // 102400 pairs
#define HID 256
#define NCOP 224
#define DIN 480
#define MBLK 32             // pairs per block in fused MFMA kernel
#define NBLK (NP / MBLK)    // 3200

typedef _Float16 half8 __attribute__((ext_vector_type(8)));
typedef _Float16 half4 __attribute__((ext_vector_type(4)));
typedef float f4 __attribute__((ext_vector_type(4)));

static __device__ __forceinline__ float silu_f(float x) {
    return x / (1.0f + __expf(-x));
}

// Swizzled byte offset into the activation LDS buffer.
// Row stride = 512 B (256 f16). XOR row&7 into bits 4..6.
static __device__ __forceinline__ int swz(int row, int colbyte) {
    return (row * 512 + colbyte) ^ ((row & 7) << 4);
}

// ---------------------------------------------------------------------------
// Precompute (fp32):
//  E1[e][n]  = e_feat[e] @ mW1[0:32]                 (400 x 256)
//  F1[b][n]  = field[b] @ mW1[32:96] + mb1           (256 x 256)
//  Fo[b][n]  = field[b] @ oW1[224:288] + ob1         (256 x 256)
//  S[b][c]   = mean(x^2) per copy: l=1 (c<64, dim3), l=2 (c 64..95, dim5)
// ---------------------------------------------------------------------------
__global__ void precompute_kernel(const float* __restrict__ h_abs,
                                  const float* __restrict__ e_feat,
                                  const float* __restrict__ field,
                                  const float* __restrict__ mW1,
                                  const float* __restrict__ mb1,
                                  const float* __restrict__ oW1,
                                  const float* __restrict__ ob1,
                                  float* __restrict__ E1,
                                  float* __restrict__ F1,
                                  float* __restrict__ Fo,
                                  float* __restrict__ S)
{
    int r = blockIdx.x;
    int t = threadIdx.x;
    if (r < NE) {
        float a = 0.f;
        #pragma unroll
        for (int k = 0; k < 32; ++k) a += e_feat[r * 32 + k] * mW1[k * HID + t];
        E1[r * HID + t] = a;
    } else if (r < NE + BB) {
        int b = r - NE;
        float a = mb1[t];
        #pragma unroll
        for (int k = 0; k < 64; ++k) a += field[b * 64 + k] * mW1[(32 + k) * HID + t];
        F1[b * HID + t] = a;
    } else if (r < NE + 2 * BB) {
        int b = r - NE - BB;
        float a = ob1[t];
        #pragma unroll
        for (int k = 0; k < 64; ++k) a += field[b * 64 + k] * oW1[(224 + k) * HID + t];
        Fo[b * HID + t] = a;
    } else {
        int b = r - NE - 2 * BB;
        if (t < 64) {
            const float* x = h_abs + b * DIN + 128 + t * 3;
            S[b * 96 + t] = (x[0]*x[0] + x[1]*x[1] + x[2]*x[2]) * (1.0f / 3.0f);
        } else if (t < 96) {
            int c = t - 64;
            const float* x = h_abs + b * DIN + 320 + c * 5;
            float s = 0.f;
            #pragma unroll
            for (int d = 0; d < 5; ++d) s += x[d] * x[d];
            S[b * 96 + t] = s * 0.2f;
        }
    }
}

// ---------------------------------------------------------------------------
// Pack weights (fp32 -> fp16). Fragment (nt, ks), lane l, elem j holds
// W[ks*32 + (l>>4)*8 + j][nt*16 + (l&15)] -- MFMA *A* operand (rows = out col n).
// ---------------------------------------------------------------------------
__global__ void pack_weights(const float* __restrict__ mW2, const float* __restrict__ mW3,
                             const float* __restrict__ oW1, const float* __restrict__ oW2,
                             _Float16* __restrict__ PB2, _Float16* __restrict__ PB3,
                             _Float16* __restrict__ PO1, _Float16* __restrict__ PO2)
{
    int blk = blockIdx.x;
    int l = threadIdx.x;
    const float* W; _Float16* P; int LD;
    if (blk < 128)      { W = mW2; P = PB2; LD = 256; }
    else if (blk < 240) { blk -= 128; W = mW3; P = PB3; LD = 224; }
    else if (blk < 352) { blk -= 240; W = oW1; P = PO1; LD = 256; }
    else                { blk -= 352; W = oW2; P = PO2; LD = 256; }
    int KST = (P == PO1) ? 7 : 8;
    int nt = blk / KST, ks = blk - nt * KST;
    int n  = nt * 16 + (l & 15);
    int k0 = ks * 32 + (l >> 4) * 8;
    half8 v;
    #pragma unroll
    for (int j = 0; j < 8; ++j) v[j] = (_Float16)W[(size_t)(k0 + j) * LD + n];
    *(half8*)&P[(size_t)(blk * 64 + l) * 8] = v;
}

// ---------------------------------------------------------------------------
// One 2-tile pass on the matrix pipe (swapped operands):
//   acc = mfma(W_frag /*A: rows=n*/, act_frag /*B: cols=pair*/, acc)
// Tiles tileA and tileA+4 (if TWO). Caller pre-initializes acc (bias fold).
// ---------------------------------------------------------------------------
template<int KST, bool TWO>
static __device__ __forceinline__ void mma_pass(const half8* __restrict__ Wp,
                                                const char* actp, int lane,
                                                int tileA, f4 acc[2][2])
{
    half8 bfA[KST], bfB[TWO ? KST : 1];
    #pragma unroll
    for (int ks = 0; ks < KST; ++ks)
        bfA[ks] = Wp[(tileA * KST + ks) * 64 + lane];
    if (TWO) {
        #pragma unroll
        for (int ks = 0; ks < KST; ++ks)
            bfB[ks] = Wp[((tileA + 4) * KST + ks) * 64 + lane];
    }

    #pragma unroll
    for (int ks = 0; ks < KST; ++ks) {
        int kb = ks * 64 + ((lane >> 4) << 4);
        half8 a[2];
        #pragma unroll
        for (int mt = 0; mt < 2; ++mt) {
            int row = mt * 16 + (lane & 15);
            a[mt] = *(const half8*)(actp + ((row * 512 + kb) ^ ((row & 7) << 4)));
        }
        #pragma unroll
        for (int mt = 0; mt < 2; ++mt)
            acc[mt][0] = __builtin_amdgcn_mfma_f32_16x16x32_f16(bfA[ks], a[mt], acc[mt][0], 0, 0, 0);
        if (TWO) {
            #pragma unroll
            for (int mt = 0; mt < 2; ++mt)
                acc[mt][1] = __builtin_amdgcn_mfma_f32_16x16x32_f16(bfB[ks], a[mt], acc[mt][1], 0, 0, 0);
        }
    }
}

// ---------------------------------------------------------------------------
// Fused kernel: 32 pairs / block, 256 threads (4 waves).
// Wave w owns n-tiles {w, w+4, w+8, w+12} via two 2-tile passes.
// Biases folded into accumulator init (MFMA C-operand adds them for free).
// ---------------------------------------------------------------------------
__global__ __launch_bounds__(256, 1)
void fused_mfma(const float* __restrict__ h_abs,
                const float* __restrict__ mb2, const float* __restrict__ mb3,
                const float* __restrict__ ob2,
                const float* __restrict__ oW3, const float* __restrict__ ob3,
                const float* __restrict__ E1, const float* __restrict__ F1,
                const float* __restrict__ Fo, const float* __restrict__ S,
                const half8* __restrict__ PB2, const half8* __restrict__ PB3,
                const half8* __restrict__ PO1, const half8* __restrict__ PO2,
                float* __restrict__ out)
{
    __shared__ char act[MBLK * 512];   // 16 KB f16 activations [32][256]
    __shared__ float sred[4][32];      // cross-wave partials (E+F fusion)

    const int t    = threadIdx.x;
    const int lane = t & 63;
    const int w    = t >> 6;           // 0..3
    const int p0   = blockIdx.x * MBLK;
    const int lr   = lane & 15;
    const int lq   = lane >> 4;

    // p = p0+row, b = b0 + (r0+row >= NE): avoids per-use int division by 400.
    const int b0 = p0 / NE;
    const int r0 = p0 - b0 * NE;

    // ---- Phase A: h1 = silu(E1[e] + F1[b])  -> act (f16) ----
    {
        #pragma unroll
        for (int i = 0; i < 4; ++i) {
            int c   = i * 256 + t;        // 0..1023 chunk id
            int row = c >> 5;
            int c0  = (c & 31) * 8;
            int e = r0 + row;
            int b = b0;
            if (e >= NE) { e -= NE; b += 1; }
            const f4* ep = (const f4*)&E1[e * HID + c0];
            const f4* fp = (const f4*)&F1[b * HID + c0];
            f4 e0 = ep[0], e1 = ep[1];
            f4 f0 = fp[0], f1 = fp[1];
            half8 hv;
            #pragma unroll
            for (int j = 0; j < 4; ++j) hv[j]     = (_Float16)silu_f(e0[j] + f0[j]);
            #pragma unroll
            for (int j = 0; j < 4; ++j) hv[4 + j] = (_Float16)silu_f(e1[j] + f1[j]);
            *(half8*)(act + swz(row, c0 * 2)) = hv;
        }
    }
    __syncthreads();

    f4 accA[2][2], accB[2][2];

    // ---- Phase B: h2 = silu(h1 @ mW2 + mb2)  [in-place] ----
    #pragma unroll
    for (int j = 0; j < 2; ++j) {
        f4 bA = *(const f4*)&mb2[(w + 4 * j) * 16 + lq * 4];
        f4 bB = *(const f4*)&mb2[(w + 8 + 4 * j) * 16 + lq * 4];
        #pragma unroll
        for (int mt = 0; mt < 2; ++mt) { accA[mt][j] = bA; accB[mt][j] = bB; }
    }
    mma_pass<8, true>(PB2, act, lane, w,     accA);
    mma_pass<8, true>(PB2, act, lane, w + 8, accB);
    __syncthreads();   // all reads of h1 done
    #pragma unroll
    for (int g = 0; g < 4; ++g) {
        int tile = w + 4 * g;
        const f4 (*acc)[2] = (g < 2) ? accA : accB;
        int j = g & 1;
        int n0 = tile * 16 + lq * 4;
        #pragma unroll
        for (int mt = 0; mt < 2; ++mt) {
            int row = mt * 16 + lr;
            half4 hv;
            #pragma unroll
            for (int r = 0; r < 4; ++r)
                hv[r] = (_Float16)silu_f(acc[mt][j][r]);
            *(half4*)(act + swz(row, n0 * 2)) = hv;
        }
    }
    __syncthreads();   // h2 visible

    // ---- Phase C: g = h2 @ mW3 + mb3 ; invariant  [in-place, cols 0..223] ----
    #pragma unroll
    for (int j = 0; j < 2; ++j) {
        int tA = w + 4 * j, tB = w + 8 + 4 * j;
        f4 bA = *(const f4*)&mb3[tA * 16 + lq * 4];
        f4 bB = (tB < 14) ? *(const f4*)&mb3[tB * 16 + lq * 4] : (f4){0,0,0,0};
        #pragma unroll
        for (int mt = 0; mt < 2; ++mt) { accA[mt][j] = bA; accB[mt][j] = bB; }
    }
    mma_pass<8, true>(PB3, act, lane, w, accA);
    if (w < 2) mma_pass<8, true >(PB3, act, lane, w + 8, accB);
    else       mma_pass<8, false>(PB3, act, lane, w + 8, accB);
    __syncthreads();
    #pragma unroll
    for (int g = 0; g < 4; ++g) {
        int tile = w + 4 * g;
        if (tile < 14) {
            const f4 (*acc)[2] = (g < 2) ? accA : accB;
            int j = g & 1;
            int n0 = tile * 16 + lq * 4;
            #pragma unroll
            for (int mt = 0; mt < 2; ++mt) {
                int row = mt * 16 + lr;
                int b = b0 + ((r0 + row) >= NE);
                half4 hv;
                if (tile < 8) {
                    f4 xh = *(const f4*)&h_abs[b * DIN + n0];
                    #pragma unroll
                    for (int r = 0; r < 4; ++r)
                        hv[r] = (_Float16)(xh[r] * acc[mt][j][r]);
                } else {
                    f4 sv = *(const f4*)&S[b * 96 + (n0 - 128)];
                    #pragma unroll
                    for (int r = 0; r < 4; ++r) {
                        float g2 = acc[mt][j][r];
                        hv[r] = (_Float16)sqrtf(g2 * g2 * sv[r] + 1e-8f);
                    }
                }
                *(half4*)(act + swz(row, n0 * 2)) = hv;
            }
        }
    }
    __syncthreads();

    // ---- Phase D: o1 = silu(inv @ oW1[0:224] + Fo[b])  [in-place] ----
    {
        int bnd[2];
        #pragma unroll
        for (int mt = 0; mt < 2; ++mt)
            bnd[mt] = b0 + ((r0 + mt * 16 + lr) >= NE);
        #pragma unroll
        for (int j = 0; j < 2; ++j)
            #pragma unroll
            for (int mt = 0; mt < 2; ++mt) {
                accA[mt][j] = *(const f4*)&Fo[bnd[mt] * HID + (w + 4 * j) * 16 + lq * 4];
                accB[mt][j] = *(const f4*)&Fo[bnd[mt] * HID + (w + 8 + 4 * j) * 16 + lq * 4];
            }
    }
    mma_pass<7, true>(PO1, act, lane, w,     accA);
    mma_pass<7, true>(PO1, act, lane, w + 8, accB);
    __syncthreads();
    #pragma unroll
    for (int g = 0; g < 4; ++g) {
        int tile = w + 4 * g;
        const f4 (*acc)[2] = (g < 2) ? accA : accB;
        int j = g & 1;
        int n0 = tile * 16 + lq * 4;
        #pragma unroll
        for (int mt = 0; mt < 2; ++mt) {
            int row = mt * 16 + lr;
            half4 hv;
            #pragma unroll
            for (int r = 0; r < 4; ++r)
                hv[r] = (_Float16)silu_f(acc[mt][j][r]);
            *(half4*)(act + swz(row, n0 * 2)) = hv;
        }
    }
    __syncthreads();

    // ---- Phase E+F fused: out[p] = silu(o1 @ oW2 + ob2) . oW3 + ob3 ----
    #pragma unroll
    for (int j = 0; j < 2; ++j) {
        f4 bA = *(const f4*)&ob2[(w + 4 * j) * 16 + lq * 4];
        f4 bB = *(const f4*)&ob2[(w + 8 + 4 * j) * 16 + lq * 4];
        #pragma unroll
        for (int mt = 0; mt < 2; ++mt) { accA[mt][j] = bA; accB[mt][j] = bB; }
    }
    mma_pass<8, true>(PO2, act, lane, w,     accA);
    mma_pass<8, true>(PO2, act, lane, w + 8, accB);
    {
        float partial[2] = {0.f, 0.f};
        #pragma unroll
        for (int g = 0; g < 4; ++g) {
            int n0 = (w + 4 * g) * 16 + lq * 4;
            const f4 (*acc)[2] = (g < 2) ? accA : accB;
            int j = g & 1;
            f4 wv = *(const f4*)&oW3[n0];
            #pragma unroll
            for (int mt = 0; mt < 2; ++mt)
                #pragma unroll
                for (int r = 0; r < 4; ++r)
                    partial[mt] += silu_f(acc[mt][j][r]) * wv[r];
        }
        #pragma unroll
        for (int mt = 0; mt < 2; ++mt) {
            float s = partial[mt];
            s += __shfl_xor(s, 16, 64);
            s += __shfl_xor(s, 32, 64);
            if (lq == 0) sred[w][mt * 16 + lr] = s;
        }
    }
    __syncthreads();
    if (t < 32) {
        float s = ob3[0];
        #pragma unroll
        for (int ww = 0; ww < 4; ++ww) s += sred[ww][t];
        out[p0 + t] = s;
    }
}

extern "C" void kernel_launch(void* const* d_in, const int* in_sizes, int n_in,
                              void* d_out, int out_size, void* d_ws, size_t ws_size,
                              hipStream_t stream) {
    const float* h_abs  = (const float*)d_in[0];
    const float* e_feat = (const float*)d_in[1];
    const float* field  = (const float*)d_in[2];
    const float* mW1 = (const float*)d_in[3];
    const float* mb1 = (const float*)d_in[4];
    const float* mW2 = (const float*)d_in[5];
    const float* mb2 = (const float*)d_in[6];
    const float* mW3 = (const float*)d_in[7];
    const float* mb3 = (const float*)d_in[8];
    const float* oW1 = (const float*)d_in[9];
    const float* ob1 = (const float*)d_in[10];
    const float* oW2 = (const float*)d_in[11];
    const float* ob2 = (const float*)d_in[12];
    const float* oW3 = (const float*)d_in[13];
    const float* ob3 = (const float*)d_in[14];
    float* out = (float*)d_out;

    // Workspace layout
    float* ws = (float*)d_ws;
    float* E1 = ws;                      // 400*256 = 102400 f
    float* F1 = E1 + NE * HID;           // 65536 f
    float* Fo = F1 + BB * HID;           // 65536 f
    float* S  = Fo + BB * HID;           // 24576 f
    _Float16* PB2 = (_Float16*)(S + BB * 96);   // 16*8*64*8 = 65536 h
    _Float16* PB3 = PB2 + 16 * 8 * 64 * 8;      // 14*8*64*8 = 57344 h
    _Float16* PO1 = PB3 + 14 * 8 * 64 * 8;      // 16*7*64*8 = 57344 h
    _Float16* PO2 = PO1 + 16 * 7 * 64 * 8;      // 16*8*64*8 = 65536 h

    precompute_kernel<<<NE + 3 * BB, 256, 0, stream>>>(
        h_abs, e_feat, field, mW1, mb1, oW1, ob1, E1, F1, Fo, S);

    pack_weights<<<480, 64, 0, stream>>>(
        mW2, mW3, oW1, oW2, PB2, PB3, PO1, PO2);

    fused_mfma<<<NBLK, 256, 0, stream>>>(
        h_abs, mb2, mb3, ob2, oW3, ob3,
        E1, F1, Fo, S,
        (const half8*)PB2, (const half8*)PB3, (const half8*)PO1, (const half8*)PO2,
        out);
}